// Round 4
// baseline (2099.759 us; speedup 1.0000x reference)
//
#include <hip/hip_runtime.h>
#include <hip/hip_bf16.h>

#define NN 100000
#define EE 1200000
#define HH 64
#define CC 10
#define GG 1000
#define NB_BUCKET 782          // ceil(NN/128)
#define BCAP 3072              // bucket capacity (mean 1536, +39 sd)

typedef unsigned int uint;
typedef unsigned short ushort;

// ---------- helpers ----------

__device__ __forceinline__ float b2fu(ushort u) {
    uint w = ((uint)u) << 16;
    float f; __builtin_memcpy(&f, &w, 4); return f;
}
__device__ __forceinline__ uint fbits(float f) { uint w; __builtin_memcpy(&w, &f, 4); return w; }
__device__ __forceinline__ float bitsf(uint w) { float f; __builtin_memcpy(&f, &w, 4); return f; }
__device__ __forceinline__ ushort f2b(float f) {
    uint w = fbits(f);
    w += 0x7FFFu + ((w >> 16) & 1u);
    return (ushort)(w >> 16);
}
__device__ __forceinline__ uint f2b2(float lo, float hi) {
    uint a = fbits(lo), b = fbits(hi);
    a += 0x7FFFu + ((a >> 16) & 1u);
    b += 0x7FFFu + ((b >> 16) & 1u);
    return (a >> 16) | (b & 0xFFFF0000u);
}
__device__ __forceinline__ float ldin(const void* p, int i, int bf) {
    if (bf) return b2fu(((const ushort*)p)[i]);
    return ((const float*)p)[i];
}
__device__ __forceinline__ void stout(void* p, int i, float v, int bf) {
    if (bf) ((ushort*)p)[i] = f2b(v);
    else    ((float*)p)[i] = v;
}

__global__ void k_detect(const uint* __restrict__ xw, int* __restrict__ flag) {
    __shared__ int cnt;
    if (threadIdx.x == 0) cnt = 0;
    __syncthreads();
    uint v = xw[threadIdx.x];
    int e = (v >> 7) & 0xFF;
    int ok = (e >= 100 && e <= 133) ? 1 : 0;
    atomicAdd(&cnt, ok);
    __syncthreads();
    if (threadIdx.x == 0) *flag = (cnt >= 96) ? 1 : 0;
}

// ---------------- CSR build: bucket sort ----------------

// Pass A: global bucket histogram via LDS
__global__ __launch_bounds__(256) void k_hist(const int* __restrict__ dst,
                                              int* __restrict__ bcnt) {
    __shared__ int hist[NB_BUCKET];
    int tid = threadIdx.x;
    for (int i = tid; i < NB_BUCKET; i += 256) hist[i] = 0;
    __syncthreads();
    for (int e = blockIdx.x * 256 + tid; e < EE; e += gridDim.x * 256)
        atomicAdd(&hist[dst[e] >> 7], 1);
    __syncthreads();
    for (int i = tid; i < NB_BUCKET; i += 256)
        if (hist[i]) atomicAdd(&bcnt[i], hist[i]);
}

// Pass B: scan bucket counts -> base, cursor
__global__ __launch_bounds__(1024) void k_bscan(const int* __restrict__ bcnt,
                                                int* __restrict__ bbase,
                                                int* __restrict__ bcur,
                                                int* __restrict__ rowptr) {
    __shared__ int s[1024];
    int tid = threadIdx.x;
    int v = (tid < NB_BUCKET) ? bcnt[tid] : 0;
    s[tid] = v;
    __syncthreads();
    for (int off = 1; off < 1024; off <<= 1) {
        int t = (tid >= off) ? s[tid - off] : 0;
        __syncthreads();
        s[tid] += t;
        __syncthreads();
    }
    if (tid < NB_BUCKET) {
        int excl = s[tid] - v;
        bbase[tid] = excl;
        bcur[tid] = excl;
        if (tid == NB_BUCKET - 1) { bbase[NB_BUCKET] = s[tid]; rowptr[NN] = s[tid]; }
    }
}

// Pass C: scatter packed (src,dst) into bucket order, block-contiguous runs
__global__ __launch_bounds__(256) void k_bscatter(const int* __restrict__ src,
                                                  const int* __restrict__ dst,
                                                  int* __restrict__ bcur,
                                                  uint2* __restrict__ ebuf) {
    __shared__ int hist[NB_BUCKET];
    __shared__ int base[NB_BUCKET];
    int tid = threadIdx.x;
    const int chunk = (EE + gridDim.x - 1) / gridDim.x;
    int e0 = blockIdx.x * chunk;
    int e1 = e0 + chunk; if (e1 > EE) e1 = EE;
    for (int i = tid; i < NB_BUCKET; i += 256) hist[i] = 0;
    __syncthreads();
    for (int e = e0 + tid; e < e1; e += 256)
        atomicAdd(&hist[dst[e] >> 7], 1);
    __syncthreads();
    for (int b = tid; b < NB_BUCKET; b += 256) {
        int c = hist[b];
        base[b] = c ? atomicAdd(&bcur[b], c) : 0;
        hist[b] = 0;
    }
    __syncthreads();
    for (int e = e0 + tid; e < e1; e += 256) {
        int d = dst[e];
        int b = d >> 7;
        int r = atomicAdd(&hist[b], 1);
        ebuf[base[b] + r] = make_uint2((uint)src[e], (uint)d);
    }
}

// Pass D: per-bucket counting sort in LDS; coalesced csr writes; rowptr + dis
__global__ __launch_bounds__(256) void k_bsort(const uint2* __restrict__ ebuf,
                                               const int* __restrict__ bbase,
                                               int* __restrict__ rowptr,
                                               float* __restrict__ dis,
                                               int* __restrict__ csr) {
    __shared__ int hist[128], sc[128], cur[128];
    __shared__ int s_src[BCAP];
    int tid = threadIdx.x;
    int b = blockIdx.x;
    int n0 = b << 7;
    int ebase = bbase[b];
    int ecnt = bbase[b + 1] - ebase;
    if (ecnt > BCAP) ecnt = BCAP;   // statistically unreachable guard
    if (tid < 128) hist[tid] = 0;
    __syncthreads();
    for (int i = tid; i < ecnt; i += 256)
        atomicAdd(&hist[ebuf[ebase + i].y & 127], 1);
    __syncthreads();
    if (tid < 128) sc[tid] = hist[tid];
    __syncthreads();
    for (int off = 1; off < 128; off <<= 1) {
        int t = (tid < 128 && tid >= off) ? sc[tid - off] : 0;
        __syncthreads();
        if (tid < 128) sc[tid] += t;
        __syncthreads();
    }
    if (tid < 128) {
        int excl = sc[tid] - hist[tid];
        cur[tid] = excl;
        int node = n0 + tid;
        if (node < NN) {
            rowptr[node] = ebase + excl;
            dis[node] = rsqrtf((float)hist[tid] + 1.0f);
        }
    }
    __syncthreads();
    for (int i = tid; i < ecnt; i += 256) {
        uint2 ed = ebuf[ebase + i];
        int p = atomicAdd(&cur[ed.y & 127], 1);
        s_src[p] = (int)ed.x;
    }
    __syncthreads();
    for (int i = tid; i < ecnt; i += 256)
        csr[ebase + i] = s_src[i];
}

// ------- GEMM: xws[N,64](bf16) = BNReLU?(A)[N,64] @ W[64,64], scaled by dis[row] -------

template<int MODE>
__global__ __launch_bounds__(256) void k_gemm(const void* __restrict__ A,
                                              const void* __restrict__ Wp,
                                              const float* __restrict__ stats,
                                              const void* __restrict__ gam,
                                              const void* __restrict__ bet,
                                              const float* __restrict__ dis,
                                              ushort* __restrict__ outb,
                                              const int* __restrict__ flag) {
    __shared__ float Wl[64 * 64];
    __shared__ float Al[64 * 68];
    __shared__ float sc[64], sh[64];
    int bf = *flag;
    int tid = threadIdx.x;
    int row0 = blockIdx.x * 64;

    if (MODE == 1 && tid < 64) {
        float m = stats[tid] * (1.0f / NN);
        float v = stats[64 + tid] * (1.0f / NN) - m * m;
        float s = rsqrtf(v + 1e-5f) * ldin(gam, tid, bf);
        sc[tid] = s;
        sh[tid] = ldin(bet, tid, bf) - m * s;
    }
    if (bf) {
        for (int i = tid; i < 4096; i += 256) Wl[i] = ldin(Wp, i, 1);
    } else {
        const float4* w4 = (const float4*)Wp;
        float4* wl4 = (float4*)Wl;
        for (int i = tid; i < 1024; i += 256) wl4[i] = w4[i];
    }
    __syncthreads();

    {
        int ra = tid >> 2, ca = (tid & 3) * 16;
        int grow = row0 + ra;
        float* dstl = &Al[ra * 68 + ca];
        if (grow < NN) {
            if (MODE == 0) {
                if (bf) {
                    const ushort* xp = (const ushort*)A + (size_t)grow * 64 + ca;
                    for (int c = 0; c < 16; ++c) dstl[c] = b2fu(xp[c]);
                } else {
                    const float4* ap = (const float4*)((const float*)A + (size_t)grow * 64 + ca);
                    for (int c = 0; c < 4; ++c) {
                        float4 v = ap[c];
                        dstl[c*4+0] = v.x; dstl[c*4+1] = v.y; dstl[c*4+2] = v.z; dstl[c*4+3] = v.w;
                    }
                }
            } else {
                const uint* hp = (const uint*)A + ((size_t)grow * 64 + ca) / 2;
                for (int cc = 0; cc < 8; ++cc) {
                    uint u = hp[cc];
                    float a = bitsf(u << 16);
                    float b = bitsf(u & 0xFFFF0000u);
                    int c = ca + cc * 2;
                    dstl[cc*2+0] = fmaxf(fmaf(a, sc[c],   sh[c]),   0.f);
                    dstl[cc*2+1] = fmaxf(fmaf(b, sc[c+1], sh[c+1]), 0.f);
                }
            }
        } else {
            for (int c = 0; c < 16; ++c) dstl[c] = 0.f;
        }
    }
    __syncthreads();

    int ra = tid >> 2, c0 = (tid & 3) * 16;
    int grow = row0 + ra;
    const float4* w4 = (const float4*)Wl;
    float4 acc0 = {0,0,0,0}, acc1 = {0,0,0,0}, acc2 = {0,0,0,0}, acc3 = {0,0,0,0};
    #pragma unroll
    for (int kk = 0; kk < 16; ++kk) {
        float4 av = *(const float4*)&Al[ra * 68 + kk * 4];
        float as[4] = {av.x, av.y, av.z, av.w};
        #pragma unroll
        for (int j = 0; j < 4; ++j) {
            int k = kk * 4 + j;
            const float4* wr = w4 + ((k * 64 + c0) >> 2);
            float4 w0 = wr[0], w1 = wr[1], w2 = wr[2], w3 = wr[3];
            float a = as[j];
            acc0.x += a*w0.x; acc0.y += a*w0.y; acc0.z += a*w0.z; acc0.w += a*w0.w;
            acc1.x += a*w1.x; acc1.y += a*w1.y; acc1.z += a*w1.z; acc1.w += a*w1.w;
            acc2.x += a*w2.x; acc2.y += a*w2.y; acc2.z += a*w2.z; acc2.w += a*w2.w;
            acc3.x += a*w3.x; acc3.y += a*w3.y; acc3.z += a*w3.z; acc3.w += a*w3.w;
        }
    }
    if (grow >= NN) return;
    float d = dis[grow];
    uint4 p0, p1;
    p0.x = f2b2(acc0.x*d, acc0.y*d); p0.y = f2b2(acc0.z*d, acc0.w*d);
    p0.z = f2b2(acc1.x*d, acc1.y*d); p0.w = f2b2(acc1.z*d, acc1.w*d);
    p1.x = f2b2(acc2.x*d, acc2.y*d); p1.y = f2b2(acc2.z*d, acc2.w*d);
    p1.z = f2b2(acc3.x*d, acc3.y*d); p1.w = f2b2(acc3.z*d, acc3.w*d);
    uint4* op = (uint4*)(outb + (size_t)grow * 64 + c0);
    op[0] = p0; op[1] = p1;
}

// ------- aggregate + fused BN stats -------

__global__ __launch_bounds__(256) void k_agg(const ushort* __restrict__ xws,
                                             const int* __restrict__ rowptr,
                                             const int* __restrict__ csr,
                                             const float* __restrict__ dis,
                                             ushort* __restrict__ hagg,
                                             float* __restrict__ stats) {
    __shared__ float ls[4][64], lq[4][64];
    int tid = threadIdx.x;
    int wid = (blockIdx.x * 256 + tid) >> 6;
    int f = tid & 63;
    int w = tid >> 6;
    float vb = 0.f;
    if (wid < NN) {
        int s = rowptr[wid], e = rowptr[wid + 1];
        float acc0 = b2fu(xws[(size_t)wid * 64 + f]);   // self term
        float acc1 = 0.f;
        int i = s;
        while (i < e) {
            int m = e - i; if (m > 64) m = 64;
            int idx = (f < m) ? csr[i + f] : 0;
            int j = 0;
            for (; j + 4 <= m; j += 4) {
                int s0 = __shfl(idx, j), s1 = __shfl(idx, j + 1);
                int s2 = __shfl(idx, j + 2), s3 = __shfl(idx, j + 3);
                float v0 = b2fu(xws[(size_t)s0 * 64 + f]);
                float v1 = b2fu(xws[(size_t)s1 * 64 + f]);
                float v2 = b2fu(xws[(size_t)s2 * 64 + f]);
                float v3 = b2fu(xws[(size_t)s3 * 64 + f]);
                acc0 += v0 + v2;
                acc1 += v1 + v3;
            }
            for (; j < m; ++j)
                acc1 += b2fu(xws[(size_t)__shfl(idx, j) * 64 + f]);
            i += m;
        }
        ushort hb = f2b((acc0 + acc1) * dis[wid]);
        hagg[(size_t)wid * 64 + f] = hb;
        vb = b2fu(hb);
    }
    ls[w][f] = vb;
    lq[w][f] = vb * vb;
    __syncthreads();
    if (w == 0) {
        float s = ls[0][f] + ls[1][f] + ls[2][f] + ls[3][f];
        float q = lq[0][f] + lq[1][f] + lq[2][f] + lq[3][f];
        atomicAdd(&stats[f], s);
        atomicAdd(&stats[64 + f], q);
    }
}

// ------- graph boundaries -------

__global__ void k_bounds(const int* __restrict__ batch, int* __restrict__ gstart) {
    int i = blockIdx.x * 256 + threadIdx.x;
    if (i > NN) return;
    int b  = (i < NN) ? batch[i] : GG;
    int pb = (i == 0) ? -1 : batch[i - 1];
    for (int g = pb + 1; g <= b; ++g) gstart[g] = i;
}

// ------- fused BN+ReLU + mean-pool + MLP head + log_softmax -------

__global__ __launch_bounds__(256) void k_poolhead(const ushort* __restrict__ hagg,
                                                  const float* __restrict__ stats,
                                                  const void* __restrict__ gam,
                                                  const void* __restrict__ bet,
                                                  const int* __restrict__ gstart,
                                                  const void* __restrict__ fc1w,
                                                  const void* __restrict__ fc1b,
                                                  const void* __restrict__ fc2w,
                                                  const void* __restrict__ fc2b,
                                                  void* __restrict__ out,
                                                  const int* __restrict__ flag) {
    __shared__ float part[4][64];
    __shared__ float pooled[64], z1[32], z2[10], slse;
    int bf = *flag;
    int g = blockIdx.x, tid = threadIdx.x;
    int w = tid >> 6, f = tid & 63;
    int s = gstart[g], e = gstart[g + 1];
    float m = stats[f] * (1.0f / NN);
    float v = stats[64 + f] * (1.0f / NN) - m * m;
    float sc = rsqrtf(v + 1e-5f) * ldin(gam, f, bf);
    float sh = ldin(bet, f, bf) - m * sc;
    float acc = 0.f;
    for (int r = s + w; r < e; r += 4)
        acc += fmaxf(fmaf(b2fu(hagg[(size_t)r * 64 + f]), sc, sh), 0.f);
    part[w][f] = acc;
    __syncthreads();
    if (w == 0)
        pooled[f] = (part[0][f] + part[1][f] + part[2][f] + part[3][f])
                  / fmaxf((float)(e - s), 1.0f);
    __syncthreads();
    if (tid < 32) {
        float a = ldin(fc1b, tid, bf);
        for (int k = 0; k < 64; ++k) a += pooled[k] * ldin(fc1w, k * 32 + tid, bf);
        z1[tid] = fmaxf(a, 0.f);
    }
    __syncthreads();
    if (tid < 10) {
        float a = ldin(fc2b, tid, bf);
        for (int k = 0; k < 32; ++k) a += z1[k] * ldin(fc2w, k * 10 + tid, bf);
        z2[tid] = a;
    }
    __syncthreads();
    if (tid == 0) {
        float mm = z2[0];
        for (int c = 1; c < 10; ++c) mm = fmaxf(mm, z2[c]);
        float ss = 0.f;
        for (int c = 0; c < 10; ++c) ss += expf(z2[c] - mm);
        slse = mm + logf(ss);
    }
    __syncthreads();
    if (tid < 10) stout(out, g * 10 + tid, z2[tid] - slse, bf);
}

// ---------------- launch ----------------

extern "C" void kernel_launch(void* const* d_in, const int* in_sizes, int n_in,
                              void* d_out, int out_size, void* d_ws, size_t ws_size,
                              hipStream_t stream) {
    const void* x     = d_in[0];
    const int*  ei    = (const int*)d_in[1];
    const int*  batch = (const int*)d_in[2];
    const int* srcp = ei;
    const int* dstp = ei + EE;
    const void* W[3]   = {d_in[3],  d_in[7],  d_in[11]};
    const void* gg_[3] = {d_in[5],  d_in[9],  d_in[13]};
    const void* be_[3] = {d_in[6],  d_in[10], d_in[14]};
    const void* fc1w = d_in[15];
    const void* fc1b = d_in[16];
    const void* fc2w = d_in[17];
    const void* fc2b = d_in[18];

    char* ws = (char*)d_ws;
    size_t off = 0;
    auto alloc = [&](size_t bytes) { size_t o = off; off = (off + bytes + 255) & ~(size_t)255; return o; };
    ushort* xws    = (ushort*)(ws + alloc((size_t)NN * HH * 2));
    ushort* hagg   = (ushort*)(ws + alloc((size_t)NN * HH * 2));
    uint2*  ebuf   = (uint2*) (ws + alloc((size_t)EE * 8));
    int*    csr    = (int*)   (ws + alloc((size_t)EE * 4));
    int*    rowptr = (int*)   (ws + alloc((size_t)(NN + 1) * 4));
    float*  dis    = (float*) (ws + alloc((size_t)NN * 4));
    int*    bcnt   = (int*)   (ws + alloc((size_t)NB_BUCKET * 4));
    int*    bbase  = (int*)   (ws + alloc((size_t)(NB_BUCKET + 1) * 4));
    int*    bcur   = (int*)   (ws + alloc((size_t)NB_BUCKET * 4));
    float*  stats  = (float*) (ws + alloc(3 * 128 * 4));     // 3 layers ping-pong
    int*    gstart = (int*)   (ws + alloc((size_t)(GG + 1) * 4));
    int*    dflag  = (int*)   (ws + alloc(256));
    if (off > ws_size) return;

    k_detect<<<1, 128, 0, stream>>>((const uint*)x, dflag);
    hipMemsetAsync(bcnt, 0, (size_t)NB_BUCKET * 4, stream);
    hipMemsetAsync(stats, 0, 3 * 128 * 4, stream);
    k_hist<<<256, 256, 0, stream>>>(dstp, bcnt);
    k_bscan<<<1, 1024, 0, stream>>>(bcnt, bbase, bcur, rowptr);
    k_bscatter<<<128, 256, 0, stream>>>(srcp, dstp, bcur, ebuf);
    k_bsort<<<NB_BUCKET, 256, 0, stream>>>(ebuf, bbase, rowptr, dis, csr);
    k_bounds<<<(NN + 256) / 256, 256, 0, stream>>>(batch, gstart);

    const int GB = (NN + 63) / 64;
    const int AB = (NN * 64 + 255) / 256;

    k_gemm<0><<<GB, 256, 0, stream>>>(x, W[0], nullptr, nullptr, nullptr, dis, xws, dflag);
    k_agg<<<AB, 256, 0, stream>>>(xws, rowptr, csr, dis, hagg, stats);

    k_gemm<1><<<GB, 256, 0, stream>>>(hagg, W[1], stats, gg_[0], be_[0], dis, xws, dflag);
    k_agg<<<AB, 256, 0, stream>>>(xws, rowptr, csr, dis, hagg, stats + 128);

    k_gemm<1><<<GB, 256, 0, stream>>>(hagg, W[2], stats + 128, gg_[1], be_[1], dis, xws, dflag);
    k_agg<<<AB, 256, 0, stream>>>(xws, rowptr, csr, dis, hagg, stats + 256);

    k_poolhead<<<GG, 256, 0, stream>>>(hagg, stats + 256, gg_[2], be_[2], gstart,
                                       fc1w, fc1b, fc2w, fc2b, d_out, dflag);
}

// Round 5
// 436.687 us; speedup vs baseline: 4.8084x; 4.8084x over previous
//
#include <hip/hip_runtime.h>
#include <hip/hip_bf16.h>

#define NN 100000
#define EE 1200000
#define HH 64
#define CC 10
#define GG 1000
#define NB_BUCKET 782          // ceil(NN/128)
#define BCAP 3072              // bucket capacity (mean 1536, +39 sd)
#define NSLICE 32              // stats atomic slices (chain depth 25000 -> 781)

typedef unsigned int uint;
typedef unsigned short ushort;

// ---------- helpers ----------

__device__ __forceinline__ float b2fu(ushort u) {
    uint w = ((uint)u) << 16;
    float f; __builtin_memcpy(&f, &w, 4); return f;
}
__device__ __forceinline__ uint fbits(float f) { uint w; __builtin_memcpy(&w, &f, 4); return w; }
__device__ __forceinline__ float bitsf(uint w) { float f; __builtin_memcpy(&f, &w, 4); return f; }
__device__ __forceinline__ ushort f2b(float f) {
    uint w = fbits(f);
    w += 0x7FFFu + ((w >> 16) & 1u);
    return (ushort)(w >> 16);
}
__device__ __forceinline__ uint f2b2(float lo, float hi) {
    uint a = fbits(lo), b = fbits(hi);
    a += 0x7FFFu + ((a >> 16) & 1u);
    b += 0x7FFFu + ((b >> 16) & 1u);
    return (a >> 16) | (b & 0xFFFF0000u);
}
__device__ __forceinline__ float ldin(const void* p, int i, int bf) {
    if (bf) return b2fu(((const ushort*)p)[i]);
    return ((const float*)p)[i];
}
__device__ __forceinline__ void stout(void* p, int i, float v, int bf) {
    if (bf) ((ushort*)p)[i] = f2b(v);
    else    ((float*)p)[i] = v;
}

__global__ void k_detect(const uint* __restrict__ xw, int* __restrict__ flag) {
    __shared__ int cnt;
    if (threadIdx.x == 0) cnt = 0;
    __syncthreads();
    uint v = xw[threadIdx.x];
    int e = (v >> 7) & 0xFF;
    int ok = (e >= 100 && e <= 133) ? 1 : 0;
    atomicAdd(&cnt, ok);
    __syncthreads();
    if (threadIdx.x == 0) *flag = (cnt >= 96) ? 1 : 0;
}

// ---------------- CSR build: bucket sort ----------------

__global__ __launch_bounds__(256) void k_hist(const int* __restrict__ dst,
                                              int* __restrict__ bcnt) {
    __shared__ int hist[NB_BUCKET];
    int tid = threadIdx.x;
    for (int i = tid; i < NB_BUCKET; i += 256) hist[i] = 0;
    __syncthreads();
    for (int e = blockIdx.x * 256 + tid; e < EE; e += gridDim.x * 256)
        atomicAdd(&hist[dst[e] >> 7], 1);
    __syncthreads();
    for (int i = tid; i < NB_BUCKET; i += 256)
        if (hist[i]) atomicAdd(&bcnt[i], hist[i]);
}

__global__ __launch_bounds__(1024) void k_bscan(const int* __restrict__ bcnt,
                                                int* __restrict__ bbase,
                                                int* __restrict__ bcur,
                                                int* __restrict__ rowptr) {
    __shared__ int s[1024];
    int tid = threadIdx.x;
    int v = (tid < NB_BUCKET) ? bcnt[tid] : 0;
    s[tid] = v;
    __syncthreads();
    for (int off = 1; off < 1024; off <<= 1) {
        int t = (tid >= off) ? s[tid - off] : 0;
        __syncthreads();
        s[tid] += t;
        __syncthreads();
    }
    if (tid < NB_BUCKET) {
        int excl = s[tid] - v;
        bbase[tid] = excl;
        bcur[tid] = excl;
        if (tid == NB_BUCKET - 1) { bbase[NB_BUCKET] = s[tid]; rowptr[NN] = s[tid]; }
    }
}

__global__ __launch_bounds__(256) void k_bscatter(const int* __restrict__ src,
                                                  const int* __restrict__ dst,
                                                  int* __restrict__ bcur,
                                                  uint2* __restrict__ ebuf) {
    __shared__ int hist[NB_BUCKET];
    __shared__ int base[NB_BUCKET];
    int tid = threadIdx.x;
    const int chunk = (EE + gridDim.x - 1) / gridDim.x;
    int e0 = blockIdx.x * chunk;
    int e1 = e0 + chunk; if (e1 > EE) e1 = EE;
    for (int i = tid; i < NB_BUCKET; i += 256) hist[i] = 0;
    __syncthreads();
    for (int e = e0 + tid; e < e1; e += 256)
        atomicAdd(&hist[dst[e] >> 7], 1);
    __syncthreads();
    for (int b = tid; b < NB_BUCKET; b += 256) {
        int c = hist[b];
        base[b] = c ? atomicAdd(&bcur[b], c) : 0;
        hist[b] = 0;
    }
    __syncthreads();
    for (int e = e0 + tid; e < e1; e += 256) {
        int d = dst[e];
        int b = d >> 7;
        int r = atomicAdd(&hist[b], 1);
        ebuf[base[b] + r] = make_uint2((uint)src[e], (uint)d);
    }
}

__global__ __launch_bounds__(256) void k_bsort(const uint2* __restrict__ ebuf,
                                               const int* __restrict__ bbase,
                                               int* __restrict__ rowptr,
                                               float* __restrict__ dis,
                                               int* __restrict__ csr) {
    __shared__ int hist[128], sc[128], cur[128];
    __shared__ int s_src[BCAP];
    int tid = threadIdx.x;
    int b = blockIdx.x;
    int n0 = b << 7;
    int ebase = bbase[b];
    int ecnt = bbase[b + 1] - ebase;
    if (ecnt > BCAP) ecnt = BCAP;
    if (tid < 128) hist[tid] = 0;
    __syncthreads();
    for (int i = tid; i < ecnt; i += 256)
        atomicAdd(&hist[ebuf[ebase + i].y & 127], 1);
    __syncthreads();
    if (tid < 128) sc[tid] = hist[tid];
    __syncthreads();
    for (int off = 1; off < 128; off <<= 1) {
        int t = (tid < 128 && tid >= off) ? sc[tid - off] : 0;
        __syncthreads();
        if (tid < 128) sc[tid] += t;
        __syncthreads();
    }
    if (tid < 128) {
        int excl = sc[tid] - hist[tid];
        cur[tid] = excl;
        int node = n0 + tid;
        if (node < NN) {
            rowptr[node] = ebase + excl;
            dis[node] = rsqrtf((float)hist[tid] + 1.0f);
        }
    }
    __syncthreads();
    for (int i = tid; i < ecnt; i += 256) {
        uint2 ed = ebuf[ebase + i];
        int p = atomicAdd(&cur[ed.y & 127], 1);
        s_src[p] = (int)ed.x;
    }
    __syncthreads();
    for (int i = tid; i < ecnt; i += 256)
        csr[ebase + i] = s_src[i];
}

// ------- GEMM: xws[N,64](bf16) = BNReLU?(A)[N,64] @ W[64,64], scaled by dis[row] -------
// stats: NSLICE slices of 128 floats; consumer sums slices.

template<int MODE>
__global__ __launch_bounds__(256) void k_gemm(const void* __restrict__ A,
                                              const void* __restrict__ Wp,
                                              const float* __restrict__ stats,
                                              const void* __restrict__ gam,
                                              const void* __restrict__ bet,
                                              const float* __restrict__ dis,
                                              ushort* __restrict__ outb,
                                              const int* __restrict__ flag) {
    __shared__ float Wl[64 * 64];
    __shared__ float Al[64 * 68];
    __shared__ float sc[64], sh[64];
    int bf = *flag;
    int tid = threadIdx.x;
    int row0 = blockIdx.x * 64;

    if (MODE == 1 && tid < 64) {
        float se = 0.f, sq = 0.f;
        #pragma unroll
        for (int sl = 0; sl < NSLICE; ++sl) {
            se += stats[sl * 128 + tid];
            sq += stats[sl * 128 + 64 + tid];
        }
        float m = se * (1.0f / NN);
        float v = sq * (1.0f / NN) - m * m;
        float s = rsqrtf(v + 1e-5f) * ldin(gam, tid, bf);
        sc[tid] = s;
        sh[tid] = ldin(bet, tid, bf) - m * s;
    }
    if (bf) {
        for (int i = tid; i < 4096; i += 256) Wl[i] = ldin(Wp, i, 1);
    } else {
        const float4* w4 = (const float4*)Wp;
        float4* wl4 = (float4*)Wl;
        for (int i = tid; i < 1024; i += 256) wl4[i] = w4[i];
    }
    __syncthreads();

    {
        int ra = tid >> 2, ca = (tid & 3) * 16;
        int grow = row0 + ra;
        float* dstl = &Al[ra * 68 + ca];
        if (grow < NN) {
            if (MODE == 0) {
                if (bf) {
                    const ushort* xp = (const ushort*)A + (size_t)grow * 64 + ca;
                    for (int c = 0; c < 16; ++c) dstl[c] = b2fu(xp[c]);
                } else {
                    const float4* ap = (const float4*)((const float*)A + (size_t)grow * 64 + ca);
                    for (int c = 0; c < 4; ++c) {
                        float4 v = ap[c];
                        dstl[c*4+0] = v.x; dstl[c*4+1] = v.y; dstl[c*4+2] = v.z; dstl[c*4+3] = v.w;
                    }
                }
            } else {
                const uint* hp = (const uint*)A + ((size_t)grow * 64 + ca) / 2;
                for (int cc = 0; cc < 8; ++cc) {
                    uint u = hp[cc];
                    float a = bitsf(u << 16);
                    float b = bitsf(u & 0xFFFF0000u);
                    int c = ca + cc * 2;
                    dstl[cc*2+0] = fmaxf(fmaf(a, sc[c],   sh[c]),   0.f);
                    dstl[cc*2+1] = fmaxf(fmaf(b, sc[c+1], sh[c+1]), 0.f);
                }
            }
        } else {
            for (int c = 0; c < 16; ++c) dstl[c] = 0.f;
        }
    }
    __syncthreads();

    int ra = tid >> 2, c0 = (tid & 3) * 16;
    int grow = row0 + ra;
    const float4* w4 = (const float4*)Wl;
    float4 acc0 = {0,0,0,0}, acc1 = {0,0,0,0}, acc2 = {0,0,0,0}, acc3 = {0,0,0,0};
    #pragma unroll
    for (int kk = 0; kk < 16; ++kk) {
        float4 av = *(const float4*)&Al[ra * 68 + kk * 4];
        float as[4] = {av.x, av.y, av.z, av.w};
        #pragma unroll
        for (int j = 0; j < 4; ++j) {
            int k = kk * 4 + j;
            const float4* wr = w4 + ((k * 64 + c0) >> 2);
            float4 w0 = wr[0], w1 = wr[1], w2 = wr[2], w3 = wr[3];
            float a = as[j];
            acc0.x += a*w0.x; acc0.y += a*w0.y; acc0.z += a*w0.z; acc0.w += a*w0.w;
            acc1.x += a*w1.x; acc1.y += a*w1.y; acc1.z += a*w1.z; acc1.w += a*w1.w;
            acc2.x += a*w2.x; acc2.y += a*w2.y; acc2.z += a*w2.z; acc2.w += a*w2.w;
            acc3.x += a*w3.x; acc3.y += a*w3.y; acc3.z += a*w3.z; acc3.w += a*w3.w;
        }
    }
    if (grow >= NN) return;
    float d = dis[grow];
    uint4 p0, p1;
    p0.x = f2b2(acc0.x*d, acc0.y*d); p0.y = f2b2(acc0.z*d, acc0.w*d);
    p0.z = f2b2(acc1.x*d, acc1.y*d); p0.w = f2b2(acc1.z*d, acc1.w*d);
    p1.x = f2b2(acc2.x*d, acc2.y*d); p1.y = f2b2(acc2.z*d, acc2.w*d);
    p1.z = f2b2(acc3.x*d, acc3.y*d); p1.w = f2b2(acc3.z*d, acc3.w*d);
    uint4* op = (uint4*)(outb + (size_t)grow * 64 + c0);
    op[0] = p0; op[1] = p1;
}

// ------- aggregate + fused BN stats (sliced atomics) -------

__global__ __launch_bounds__(256) void k_agg(const ushort* __restrict__ xws,
                                             const int* __restrict__ rowptr,
                                             const int* __restrict__ csr,
                                             const float* __restrict__ dis,
                                             ushort* __restrict__ hagg,
                                             float* __restrict__ stats) {
    __shared__ float ls[4][64], lq[4][64];
    int tid = threadIdx.x;
    int wid = (blockIdx.x * 256 + tid) >> 6;
    int f = tid & 63;
    int w = tid >> 6;
    float vb = 0.f;
    if (wid < NN) {
        int s = rowptr[wid], e = rowptr[wid + 1];
        float acc0 = b2fu(xws[(size_t)wid * 64 + f]);   // self term
        float acc1 = 0.f;
        int i = s;
        while (i < e) {
            int m = e - i; if (m > 64) m = 64;
            int idx = (f < m) ? csr[i + f] : 0;
            int j = 0;
            for (; j + 4 <= m; j += 4) {
                int s0 = __shfl(idx, j), s1 = __shfl(idx, j + 1);
                int s2 = __shfl(idx, j + 2), s3 = __shfl(idx, j + 3);
                float v0 = b2fu(xws[(size_t)s0 * 64 + f]);
                float v1 = b2fu(xws[(size_t)s1 * 64 + f]);
                float v2 = b2fu(xws[(size_t)s2 * 64 + f]);
                float v3 = b2fu(xws[(size_t)s3 * 64 + f]);
                acc0 += v0 + v2;
                acc1 += v1 + v3;
            }
            for (; j < m; ++j)
                acc1 += b2fu(xws[(size_t)__shfl(idx, j) * 64 + f]);
            i += m;
        }
        ushort hb = f2b((acc0 + acc1) * dis[wid]);
        hagg[(size_t)wid * 64 + f] = hb;
        vb = b2fu(hb);
    }
    ls[w][f] = vb;
    lq[w][f] = vb * vb;
    __syncthreads();
    if (w == 0) {
        float s = ls[0][f] + ls[1][f] + ls[2][f] + ls[3][f];
        float q = lq[0][f] + lq[1][f] + lq[2][f] + lq[3][f];
        float* sl = stats + (blockIdx.x & (NSLICE - 1)) * 128;
        atomicAdd(&sl[f], s);
        atomicAdd(&sl[64 + f], q);
    }
}

// ------- graph boundaries -------

__global__ void k_bounds(const int* __restrict__ batch, int* __restrict__ gstart) {
    int i = blockIdx.x * 256 + threadIdx.x;
    if (i > NN) return;
    int b  = (i < NN) ? batch[i] : GG;
    int pb = (i == 0) ? -1 : batch[i - 1];
    for (int g = pb + 1; g <= b; ++g) gstart[g] = i;
}

// ------- fused BN+ReLU + mean-pool + MLP head + log_softmax -------

__global__ __launch_bounds__(256) void k_poolhead(const ushort* __restrict__ hagg,
                                                  const float* __restrict__ stats,
                                                  const void* __restrict__ gam,
                                                  const void* __restrict__ bet,
                                                  const int* __restrict__ gstart,
                                                  const void* __restrict__ fc1w,
                                                  const void* __restrict__ fc1b,
                                                  const void* __restrict__ fc2w,
                                                  const void* __restrict__ fc2b,
                                                  void* __restrict__ out,
                                                  const int* __restrict__ flag) {
    __shared__ float part[4][64];
    __shared__ float pooled[64], z1[32], z2[10], slse;
    int bf = *flag;
    int g = blockIdx.x, tid = threadIdx.x;
    int w = tid >> 6, f = tid & 63;
    int s = gstart[g], e = gstart[g + 1];
    float se = 0.f, sq = 0.f;
    #pragma unroll
    for (int sl = 0; sl < NSLICE; ++sl) {
        se += stats[sl * 128 + f];
        sq += stats[sl * 128 + 64 + f];
    }
    float m = se * (1.0f / NN);
    float v = sq * (1.0f / NN) - m * m;
    float sc = rsqrtf(v + 1e-5f) * ldin(gam, f, bf);
    float sh = ldin(bet, f, bf) - m * sc;
    float acc = 0.f;
    for (int r = s + w; r < e; r += 4)
        acc += fmaxf(fmaf(b2fu(hagg[(size_t)r * 64 + f]), sc, sh), 0.f);
    part[w][f] = acc;
    __syncthreads();
    if (w == 0)
        pooled[f] = (part[0][f] + part[1][f] + part[2][f] + part[3][f])
                  / fmaxf((float)(e - s), 1.0f);
    __syncthreads();
    if (tid < 32) {
        float a = ldin(fc1b, tid, bf);
        for (int k = 0; k < 64; ++k) a += pooled[k] * ldin(fc1w, k * 32 + tid, bf);
        z1[tid] = fmaxf(a, 0.f);
    }
    __syncthreads();
    if (tid < 10) {
        float a = ldin(fc2b, tid, bf);
        for (int k = 0; k < 32; ++k) a += z1[k] * ldin(fc2w, k * 10 + tid, bf);
        z2[tid] = a;
    }
    __syncthreads();
    if (tid == 0) {
        float mm = z2[0];
        for (int c = 1; c < 10; ++c) mm = fmaxf(mm, z2[c]);
        float ss = 0.f;
        for (int c = 0; c < 10; ++c) ss += expf(z2[c] - mm);
        slse = mm + logf(ss);
    }
    __syncthreads();
    if (tid < 10) stout(out, g * 10 + tid, z2[tid] - slse, bf);
}

// ---------------- launch ----------------

extern "C" void kernel_launch(void* const* d_in, const int* in_sizes, int n_in,
                              void* d_out, int out_size, void* d_ws, size_t ws_size,
                              hipStream_t stream) {
    const void* x     = d_in[0];
    const int*  ei    = (const int*)d_in[1];
    const int*  batch = (const int*)d_in[2];
    const int* srcp = ei;
    const int* dstp = ei + EE;
    const void* W[3]   = {d_in[3],  d_in[7],  d_in[11]};
    const void* gg_[3] = {d_in[5],  d_in[9],  d_in[13]};
    const void* be_[3] = {d_in[6],  d_in[10], d_in[14]};
    const void* fc1w = d_in[15];
    const void* fc1b = d_in[16];
    const void* fc2w = d_in[17];
    const void* fc2b = d_in[18];

    char* ws = (char*)d_ws;
    size_t off = 0;
    auto alloc = [&](size_t bytes) { size_t o = off; off = (off + bytes + 255) & ~(size_t)255; return o; };
    ushort* xws    = (ushort*)(ws + alloc((size_t)NN * HH * 2));
    ushort* hagg   = (ushort*)(ws + alloc((size_t)NN * HH * 2));
    uint2*  ebuf   = (uint2*) (ws + alloc((size_t)EE * 8));
    int*    csr    = (int*)   (ws + alloc((size_t)EE * 4));
    int*    rowptr = (int*)   (ws + alloc((size_t)(NN + 1) * 4));
    float*  dis    = (float*) (ws + alloc((size_t)NN * 4));
    int*    bcnt   = (int*)   (ws + alloc((size_t)NB_BUCKET * 4));
    int*    bbase  = (int*)   (ws + alloc((size_t)(NB_BUCKET + 1) * 4));
    int*    bcur   = (int*)   (ws + alloc((size_t)NB_BUCKET * 4));
    float*  stats  = (float*) (ws + alloc((size_t)3 * NSLICE * 128 * 4));
    int*    gstart = (int*)   (ws + alloc((size_t)(GG + 1) * 4));
    int*    dflag  = (int*)   (ws + alloc(256));
    if (off > ws_size) return;

    k_detect<<<1, 128, 0, stream>>>((const uint*)x, dflag);
    hipMemsetAsync(bcnt, 0, (size_t)NB_BUCKET * 4, stream);
    hipMemsetAsync(stats, 0, (size_t)3 * NSLICE * 128 * 4, stream);
    k_hist<<<256, 256, 0, stream>>>(dstp, bcnt);
    k_bscan<<<1, 1024, 0, stream>>>(bcnt, bbase, bcur, rowptr);
    k_bscatter<<<128, 256, 0, stream>>>(srcp, dstp, bcur, ebuf);
    k_bsort<<<NB_BUCKET, 256, 0, stream>>>(ebuf, bbase, rowptr, dis, csr);
    k_bounds<<<(NN + 256) / 256, 256, 0, stream>>>(batch, gstart);

    const int GB = (NN + 63) / 64;
    const int AB = (NN * 64 + 255) / 256;
    const int SL = NSLICE * 128;

    k_gemm<0><<<GB, 256, 0, stream>>>(x, W[0], nullptr, nullptr, nullptr, dis, xws, dflag);
    k_agg<<<AB, 256, 0, stream>>>(xws, rowptr, csr, dis, hagg, stats);

    k_gemm<1><<<GB, 256, 0, stream>>>(hagg, W[1], stats, gg_[0], be_[0], dis, xws, dflag);
    k_agg<<<AB, 256, 0, stream>>>(xws, rowptr, csr, dis, hagg, stats + SL);

    k_gemm<1><<<GB, 256, 0, stream>>>(hagg, W[2], stats + SL, gg_[1], be_[1], dis, xws, dflag);
    k_agg<<<AB, 256, 0, stream>>>(xws, rowptr, csr, dis, hagg, stats + 2 * SL);

    k_poolhead<<<GG, 256, 0, stream>>>(hagg, stats + 2 * SL, gg_[2], be_[2], gstart,
                                       fc1w, fc1b, fc2w, fc2b, d_out, dflag);
}